// Round 1
// baseline (4154.916 us; speedup 1.0000x reference)
//
#include <hip/hip_runtime.h>

#define N_NODES 50000
#define N_EDGES 1600000
#define IN_FEATS 512
#define N_HIDDEN 128
#define N_CLASSES 40

// ---------------------------------------------------------------------------
// degrees: deg_out[src[e]]++, deg_in[dst[e]]++
__global__ void deg_kernel(const int* __restrict__ src, const int* __restrict__ dst,
                           int* __restrict__ deg_out, int* __restrict__ deg_in) {
    int e = blockIdx.x * blockDim.x + threadIdx.x;
    if (e < N_EDGES) {
        atomicAdd(&deg_out[src[e]], 1);
        atomicAdd(&deg_in[dst[e]], 1);
    }
}

// norms: rsqrt(max(deg,1))
__global__ void norm_kernel(const int* __restrict__ deg_out, const int* __restrict__ deg_in,
                            float* __restrict__ norm_src, float* __restrict__ norm_dst) {
    int n = blockIdx.x * blockDim.x + threadIdx.x;
    if (n < N_NODES) {
        norm_src[n] = rsqrtf(fmaxf((float)deg_out[n], 1.0f));
        norm_dst[n] = rsqrtf(fmaxf((float)deg_in[n], 1.0f));
    }
}

// ---------------------------------------------------------------------------
// GEMM1: H[n, 0:128] = (X[n, 0:512] @ W1) * norm_src[n]
// 128x128 tile, TK=16, 256 threads, 8x8 register blocking. f32 VALU.
__global__ __launch_bounds__(256) void gemm1_kernel(
    const float* __restrict__ X, const float* __restrict__ W,
    const float* __restrict__ norm_src, float* __restrict__ H) {
    __shared__ float Xs[16][132];  // [k][row], +4 pad to soften store conflicts
    __shared__ float Ws[16][132];  // [k][col]
    const int tid = threadIdx.x;
    const int row0 = blockIdx.x * 128;
    const int trow = (tid >> 4) * 8;   // 0..120
    const int tcol = (tid & 15) * 8;   // 0..120

    float acc[8][8];
#pragma unroll
    for (int i = 0; i < 8; i++)
#pragma unroll
        for (int j = 0; j < 8; j++) acc[i][j] = 0.0f;

    for (int k0 = 0; k0 < IN_FEATS; k0 += 16) {
        // stage X tile (128 rows x 16 k), transposed into Xs[k][row]
#pragma unroll
        for (int l = 0; l < 2; l++) {
            int s = tid + l * 256;          // 0..511 float4 slots
            int r = s >> 2;                 // 0..127
            int kq = (s & 3) * 4;           // 0,4,8,12
            int grow = row0 + r;
            float4 v = make_float4(0.f, 0.f, 0.f, 0.f);
            if (grow < N_NODES)
                v = *(const float4*)&X[(size_t)grow * IN_FEATS + k0 + kq];
            Xs[kq + 0][r] = v.x;
            Xs[kq + 1][r] = v.y;
            Xs[kq + 2][r] = v.z;
            Xs[kq + 3][r] = v.w;
        }
        // stage W tile (16 k x 128 cols)
#pragma unroll
        for (int l = 0; l < 2; l++) {
            int s = tid + l * 256;
            int k = s >> 5;                 // 0..15
            int c = (s & 31) * 4;           // 0..124
            *(float4*)&Ws[k][c] = *(const float4*)&W[(size_t)(k0 + k) * N_HIDDEN + c];
        }
        __syncthreads();
#pragma unroll
        for (int k = 0; k < 16; k++) {
            float a[8], b[8];
            *(float4*)&a[0] = *(const float4*)&Xs[k][trow];
            *(float4*)&a[4] = *(const float4*)&Xs[k][trow + 4];
            *(float4*)&b[0] = *(const float4*)&Ws[k][tcol];
            *(float4*)&b[4] = *(const float4*)&Ws[k][tcol + 4];
#pragma unroll
            for (int i = 0; i < 8; i++)
#pragma unroll
                for (int j = 0; j < 8; j++)
                    acc[i][j] = fmaf(a[i], b[j], acc[i][j]);
        }
        __syncthreads();
    }
    // epilogue: scale rows by norm_src, store
#pragma unroll
    for (int i = 0; i < 8; i++) {
        int grow = row0 + trow + i;
        if (grow < N_NODES) {
            float sc = norm_src[grow];
            float4 v0 = make_float4(acc[i][0] * sc, acc[i][1] * sc, acc[i][2] * sc, acc[i][3] * sc);
            float4 v1 = make_float4(acc[i][4] * sc, acc[i][5] * sc, acc[i][6] * sc, acc[i][7] * sc);
            *(float4*)&H[(size_t)grow * N_HIDDEN + tcol] = v0;
            *(float4*)&H[(size_t)grow * N_HIDDEN + tcol + 4] = v1;
        }
    }
}

// ---------------------------------------------------------------------------
// edge scatter layer 1: AGG[dst[e], f] += H[src[e], f], 32 threads/edge x float4
__global__ void edge1_kernel(const int* __restrict__ src, const int* __restrict__ dst,
                             const float* __restrict__ H, float* __restrict__ AGG) {
    long long gid = (long long)blockIdx.x * blockDim.x + threadIdx.x;
    int e = (int)(gid >> 5);
    if (e >= N_EDGES) return;
    int f = ((int)gid & 31) * 4;
    int s = src[e], d = dst[e];
    float4 v = *(const float4*)&H[(size_t)s * N_HIDDEN + f];
    float* o = &AGG[(size_t)d * N_HIDDEN + f];
    unsafeAtomicAdd(o + 0, v.x);
    unsafeAtomicAdd(o + 1, v.y);
    unsafeAtomicAdd(o + 2, v.z);
    unsafeAtomicAdd(o + 3, v.w);
}

// finish1 (in place): h1 = relu(agg * norm_dst[n] + b1[f])
__global__ void finish1_kernel(float* __restrict__ AGG, const float* __restrict__ norm_dst,
                               const float* __restrict__ b1) {
    int gid = blockIdx.x * blockDim.x + threadIdx.x;  // float4 index
    if (gid >= N_NODES * N_HIDDEN / 4) return;
    int n = gid >> 5;              // 32 float4 per row
    int f = (gid & 31) * 4;
    float nd = norm_dst[n];
    float4 v = *(float4*)&AGG[(size_t)gid * 4];
    float4 b = *(const float4*)&b1[f];
    v.x = fmaxf(v.x * nd + b.x, 0.f);
    v.y = fmaxf(v.y * nd + b.y, 0.f);
    v.z = fmaxf(v.z * nd + b.z, 0.f);
    v.w = fmaxf(v.w * nd + b.w, 0.f);
    *(float4*)&AGG[(size_t)gid * 4] = v;
}

// ---------------------------------------------------------------------------
// GEMM2: H2[n, 0:40] = (H1[n, 0:128] @ W2) * norm_src[n]; one wave per row
__global__ __launch_bounds__(256) void gemm2_kernel(
    const float* __restrict__ H1, const float* __restrict__ W2,
    const float* __restrict__ norm_src, float* __restrict__ H2) {
    __shared__ float Ws[N_HIDDEN * N_CLASSES];  // 20480 B
    int tid = threadIdx.x;
    for (int i = tid; i < N_HIDDEN * N_CLASSES; i += 256) Ws[i] = W2[i];
    __syncthreads();
    int wave = tid >> 6;
    int lane = tid & 63;
    int row = blockIdx.x * 4 + wave;
    if (row >= N_NODES || lane >= N_CLASSES) return;
    const float* h = &H1[(size_t)row * N_HIDDEN];
    float acc = 0.f;
#pragma unroll 8
    for (int k = 0; k < N_HIDDEN; k++)
        acc = fmaf(h[k], Ws[k * N_CLASSES + lane], acc);
    H2[(size_t)row * N_CLASSES + lane] = acc * norm_src[row];
}

// edge scatter layer 2: AGG2[dst[e], f] += H2[src[e], f], 10 float4 per edge
__global__ void edge2_kernel(const int* __restrict__ src, const int* __restrict__ dst,
                             const float* __restrict__ H2, float* __restrict__ AGG2) {
    long long gid = (long long)blockIdx.x * blockDim.x + threadIdx.x;
    int e = (int)(gid / 10);
    if (e >= N_EDGES) return;
    int f = (int)(gid % 10) * 4;
    int s = src[e], d = dst[e];
    float4 v = *(const float4*)&H2[(size_t)s * N_CLASSES + f];
    float* o = &AGG2[(size_t)d * N_CLASSES + f];
    unsafeAtomicAdd(o + 0, v.x);
    unsafeAtomicAdd(o + 1, v.y);
    unsafeAtomicAdd(o + 2, v.z);
    unsafeAtomicAdd(o + 3, v.w);
}

// finish2: out = agg2 * norm_dst[n] + b2[c]
__global__ void finish2_kernel(const float* __restrict__ AGG2, const float* __restrict__ norm_dst,
                               const float* __restrict__ b2, float* __restrict__ OUT) {
    int gid = blockIdx.x * blockDim.x + threadIdx.x;  // float4 index
    if (gid >= N_NODES * N_CLASSES / 4) return;
    int n = gid / 10;              // 10 float4 per row
    int f = (gid % 10) * 4;
    float nd = norm_dst[n];
    float4 v = *(const float4*)&AGG2[(size_t)gid * 4];
    float4 b = *(const float4*)&b2[f];
    v.x = v.x * nd + b.x;
    v.y = v.y * nd + b.y;
    v.z = v.z * nd + b.z;
    v.w = v.w * nd + b.w;
    *(float4*)&OUT[(size_t)gid * 4] = v;
}

// ---------------------------------------------------------------------------
extern "C" void kernel_launch(void* const* d_in, const int* in_sizes, int n_in,
                              void* d_out, int out_size, void* d_ws, size_t ws_size,
                              hipStream_t stream) {
    const float* X   = (const float*)d_in[0];
    const float* W1  = (const float*)d_in[1];
    const float* b1  = (const float*)d_in[2];
    const float* W2  = (const float*)d_in[3];
    const float* b2  = (const float*)d_in[4];
    const int*   src = (const int*)d_in[5];
    const int*   dst = (const int*)d_in[6];
    float* out = (float*)d_out;

    // workspace layout (floats): norm_src | norm_dst | deg_out | deg_in | H | AGG | AGG2
    float* norm_src = (float*)d_ws;
    float* norm_dst = norm_src + N_NODES;
    int*   deg_out  = (int*)(norm_dst + N_NODES);
    int*   deg_in   = deg_out + N_NODES;
    float* H        = (float*)(deg_in + N_NODES);              // 50000*128
    float* AGG      = H + (size_t)N_NODES * N_HIDDEN;          // 50000*128 (becomes H1 in place)
    float* AGG2     = AGG + (size_t)N_NODES * N_HIDDEN;        // 50000*40
    float* H2       = H;                                       // reuse H for layer-2 pre-agg

    hipMemsetAsync(deg_out, 0, 2 * (size_t)N_NODES * sizeof(int), stream);
    deg_kernel<<<(N_EDGES + 255) / 256, 256, 0, stream>>>(src, dst, deg_out, deg_in);
    norm_kernel<<<(N_NODES + 255) / 256, 256, 0, stream>>>(deg_out, deg_in, norm_src, norm_dst);

    gemm1_kernel<<<(N_NODES + 127) / 128, 256, 0, stream>>>(X, W1, norm_src, H);

    hipMemsetAsync(AGG, 0, (size_t)N_NODES * N_HIDDEN * sizeof(float), stream);
    edge1_kernel<<<(int)(((long long)N_EDGES * 32 + 255) / 256), 256, 0, stream>>>(src, dst, H, AGG);
    finish1_kernel<<<(N_NODES * N_HIDDEN / 4 + 255) / 256, 256, 0, stream>>>(AGG, norm_dst, b1);

    gemm2_kernel<<<(N_NODES + 3) / 4, 256, 0, stream>>>(AGG, W2, norm_src, H2);

    hipMemsetAsync(AGG2, 0, (size_t)N_NODES * N_CLASSES * sizeof(float), stream);
    edge2_kernel<<<(int)(((long long)N_EDGES * 10 + 255) / 256), 256, 0, stream>>>(src, dst, H2, AGG2);
    finish2_kernel<<<(N_NODES * N_CLASSES / 4 + 255) / 256, 256, 0, stream>>>(AGG2, norm_dst, b2, out);
}

// Round 2
// 870.954 us; speedup vs baseline: 4.7705x; 4.7705x over previous
//
#include <hip/hip_runtime.h>

#define N_NODES 50000
#define N_EDGES 1600000
#define IN_FEATS 512
#define N_HIDDEN 128
#define N_CLASSES 40

// ---------------------------------------------------------------------------
// degrees: deg_out[src[e]]++, deg_in[dst[e]]++
__global__ void deg_kernel(const int* __restrict__ src, const int* __restrict__ dst,
                           int* __restrict__ deg_out, int* __restrict__ deg_in) {
    int e = blockIdx.x * blockDim.x + threadIdx.x;
    if (e < N_EDGES) {
        atomicAdd(&deg_out[src[e]], 1);
        atomicAdd(&deg_in[dst[e]], 1);
    }
}

// norms: rsqrt(max(deg,1))
__global__ void norm_kernel(const int* __restrict__ deg_out, const int* __restrict__ deg_in,
                            float* __restrict__ norm_src, float* __restrict__ norm_dst) {
    int n = blockIdx.x * blockDim.x + threadIdx.x;
    if (n < N_NODES) {
        norm_src[n] = rsqrtf(fmaxf((float)deg_out[n], 1.0f));
        norm_dst[n] = rsqrtf(fmaxf((float)deg_in[n], 1.0f));
    }
}

// ---------------------------------------------------------------------------
// single-block exclusive scan of deg_in -> offsets[0..N], cursor copy
// 1024 threads x 49 items = 50176 >= 50000
__global__ __launch_bounds__(1024) void scan_kernel(const int* __restrict__ deg_in,
                                                    int* __restrict__ offsets,
                                                    int* __restrict__ cursor) {
    __shared__ int part[1024];
    const int t = threadIdx.x;
    const int beg = t * 49;
    const int end = min(beg + 49, N_NODES);
    int s = 0;
    for (int i = beg; i < end; i++) s += deg_in[i];
    part[t] = s;
    __syncthreads();
    for (int off = 1; off < 1024; off <<= 1) {
        int v = (t >= off) ? part[t - off] : 0;
        __syncthreads();
        part[t] += v;
        __syncthreads();
    }
    int run = (t == 0) ? 0 : part[t - 1];  // exclusive base for this chunk
    for (int i = beg; i < end; i++) {
        offsets[i] = run;
        cursor[i] = run;
        run += deg_in[i];
    }
    if (t == 1023) offsets[N_NODES] = part[1023];  // == N_EDGES
}

// counting-sort fill: bucket edges by dst, storing src index
__global__ void fill_kernel(const int* __restrict__ src, const int* __restrict__ dst,
                            int* __restrict__ cursor, int* __restrict__ sorted_src) {
    int e = blockIdx.x * blockDim.x + threadIdx.x;
    if (e < N_EDGES) {
        int pos = atomicAdd(&cursor[dst[e]], 1);
        sorted_src[pos] = src[e];
    }
}

// ---------------------------------------------------------------------------
// GEMM1: H[n, 0:128] = (X[n, 0:512] @ W1) * norm_src[n]
// 128x128 tile, TK=16, 256 threads, 8x8 register blocking. f32 VALU.
__global__ __launch_bounds__(256) void gemm1_kernel(
    const float* __restrict__ X, const float* __restrict__ W,
    const float* __restrict__ norm_src, float* __restrict__ H) {
    __shared__ float Xs[16][132];
    __shared__ float Ws[16][132];
    const int tid = threadIdx.x;
    const int row0 = blockIdx.x * 128;
    const int trow = (tid >> 4) * 8;
    const int tcol = (tid & 15) * 8;

    float acc[8][8];
#pragma unroll
    for (int i = 0; i < 8; i++)
#pragma unroll
        for (int j = 0; j < 8; j++) acc[i][j] = 0.0f;

    for (int k0 = 0; k0 < IN_FEATS; k0 += 16) {
#pragma unroll
        for (int l = 0; l < 2; l++) {
            int s = tid + l * 256;
            int r = s >> 2;
            int kq = (s & 3) * 4;
            int grow = row0 + r;
            float4 v = make_float4(0.f, 0.f, 0.f, 0.f);
            if (grow < N_NODES)
                v = *(const float4*)&X[(size_t)grow * IN_FEATS + k0 + kq];
            Xs[kq + 0][r] = v.x;
            Xs[kq + 1][r] = v.y;
            Xs[kq + 2][r] = v.z;
            Xs[kq + 3][r] = v.w;
        }
#pragma unroll
        for (int l = 0; l < 2; l++) {
            int s = tid + l * 256;
            int k = s >> 5;
            int c = (s & 31) * 4;
            *(float4*)&Ws[k][c] = *(const float4*)&W[(size_t)(k0 + k) * N_HIDDEN + c];
        }
        __syncthreads();
#pragma unroll
        for (int k = 0; k < 16; k++) {
            float a[8], b[8];
            *(float4*)&a[0] = *(const float4*)&Xs[k][trow];
            *(float4*)&a[4] = *(const float4*)&Xs[k][trow + 4];
            *(float4*)&b[0] = *(const float4*)&Ws[k][tcol];
            *(float4*)&b[4] = *(const float4*)&Ws[k][tcol + 4];
#pragma unroll
            for (int i = 0; i < 8; i++)
#pragma unroll
                for (int j = 0; j < 8; j++)
                    acc[i][j] = fmaf(a[i], b[j], acc[i][j]);
        }
        __syncthreads();
    }
#pragma unroll
    for (int i = 0; i < 8; i++) {
        int grow = row0 + trow + i;
        if (grow < N_NODES) {
            float sc = norm_src[grow];
            float4 v0 = make_float4(acc[i][0] * sc, acc[i][1] * sc, acc[i][2] * sc, acc[i][3] * sc);
            float4 v1 = make_float4(acc[i][4] * sc, acc[i][5] * sc, acc[i][6] * sc, acc[i][7] * sc);
            *(float4*)&H[(size_t)grow * N_HIDDEN + tcol] = v0;
            *(float4*)&H[(size_t)grow * N_HIDDEN + tcol + 4] = v1;
        }
    }
}

// ---------------------------------------------------------------------------
// agg1: one wave per dst node; gather H[src] rows (128 f = float2/lane), fuse
// norm_dst scale + bias + relu.
__global__ __launch_bounds__(256) void agg1_kernel(
    const int* __restrict__ offsets, const int* __restrict__ sorted_src,
    const float* __restrict__ H, const float* __restrict__ norm_dst,
    const float* __restrict__ b1, float* __restrict__ H1) {
    int wave = (blockIdx.x * 256 + threadIdx.x) >> 6;
    int lane = threadIdx.x & 63;
    if (wave >= N_NODES) return;
    int start = offsets[wave], end = offsets[wave + 1];
    float2 acc = make_float2(0.f, 0.f);
    for (int base = start; base < end; base += 64) {
        int n = min(64, end - base);
        int eidx = (lane < n) ? sorted_src[base + lane] : 0;
        for (int j = 0; j < n; j++) {
            int s = __shfl(eidx, j);
            float2 v = *(const float2*)&H[(size_t)s * N_HIDDEN + lane * 2];
            acc.x += v.x;
            acc.y += v.y;
        }
    }
    float nd = norm_dst[wave];
    float2 b = *(const float2*)&b1[lane * 2];
    acc.x = fmaxf(acc.x * nd + b.x, 0.f);
    acc.y = fmaxf(acc.y * nd + b.y, 0.f);
    *(float2*)&H1[(size_t)wave * N_HIDDEN + lane * 2] = acc;
}

// ---------------------------------------------------------------------------
// GEMM2: H2[n, 0:40] = (H1[n, 0:128] @ W2) * norm_src[n]; one wave per row
__global__ __launch_bounds__(256) void gemm2_kernel(
    const float* __restrict__ H1, const float* __restrict__ W2,
    const float* __restrict__ norm_src, float* __restrict__ H2) {
    __shared__ float Ws[N_HIDDEN * N_CLASSES];
    int tid = threadIdx.x;
    for (int i = tid; i < N_HIDDEN * N_CLASSES; i += 256) Ws[i] = W2[i];
    __syncthreads();
    int wave = tid >> 6;
    int lane = tid & 63;
    int row = blockIdx.x * 4 + wave;
    if (row >= N_NODES || lane >= N_CLASSES) return;
    const float* h = &H1[(size_t)row * N_HIDDEN];
    float acc = 0.f;
#pragma unroll 8
    for (int k = 0; k < N_HIDDEN; k++)
        acc = fmaf(h[k], Ws[k * N_CLASSES + lane], acc);
    H2[(size_t)row * N_CLASSES + lane] = acc * norm_src[row];
}

// ---------------------------------------------------------------------------
// agg2: one wave per dst node; gather H2[src] rows (40 f, lanes 0..39), fuse
// norm_dst scale + bias. Writes final output.
__global__ __launch_bounds__(256) void agg2_kernel(
    const int* __restrict__ offsets, const int* __restrict__ sorted_src,
    const float* __restrict__ H2, const float* __restrict__ norm_dst,
    const float* __restrict__ b2, float* __restrict__ OUT) {
    int wave = (blockIdx.x * 256 + threadIdx.x) >> 6;
    int lane = threadIdx.x & 63;
    if (wave >= N_NODES) return;
    int start = offsets[wave], end = offsets[wave + 1];
    float acc = 0.f;
    for (int base = start; base < end; base += 64) {
        int n = min(64, end - base);
        int eidx = (lane < n) ? sorted_src[base + lane] : 0;
        for (int j = 0; j < n; j++) {
            int s = __shfl(eidx, j);
            if (lane < N_CLASSES) acc += H2[(size_t)s * N_CLASSES + lane];
        }
    }
    if (lane < N_CLASSES)
        OUT[(size_t)wave * N_CLASSES + lane] = acc * norm_dst[wave] + b2[lane];
}

// ---------------------------------------------------------------------------
extern "C" void kernel_launch(void* const* d_in, const int* in_sizes, int n_in,
                              void* d_out, int out_size, void* d_ws, size_t ws_size,
                              hipStream_t stream) {
    const float* X   = (const float*)d_in[0];
    const float* W1  = (const float*)d_in[1];
    const float* b1  = (const float*)d_in[2];
    const float* W2  = (const float*)d_in[3];
    const float* b2  = (const float*)d_in[4];
    const int*   src = (const int*)d_in[5];
    const int*   dst = (const int*)d_in[6];
    float* out = (float*)d_out;

    // workspace layout
    float* norm_src   = (float*)d_ws;
    float* norm_dst   = norm_src + N_NODES;
    int*   deg_out    = (int*)(norm_dst + N_NODES);
    int*   deg_in     = deg_out + N_NODES;
    int*   offsets    = deg_in + N_NODES;          // N_NODES+1 (padded to +16)
    int*   cursor     = offsets + N_NODES + 16;
    int*   sorted_src = cursor + N_NODES;          // N_EDGES
    float* H          = (float*)(sorted_src + N_EDGES);   // 50000*128
    float* H1         = H + (size_t)N_NODES * N_HIDDEN;   // 50000*128
    float* H2         = H;                                // reuse for layer-2 pre-agg

    hipMemsetAsync(deg_out, 0, 2 * (size_t)N_NODES * sizeof(int), stream);
    deg_kernel<<<(N_EDGES + 255) / 256, 256, 0, stream>>>(src, dst, deg_out, deg_in);
    norm_kernel<<<(N_NODES + 255) / 256, 256, 0, stream>>>(deg_out, deg_in, norm_src, norm_dst);
    scan_kernel<<<1, 1024, 0, stream>>>(deg_in, offsets, cursor);
    fill_kernel<<<(N_EDGES + 255) / 256, 256, 0, stream>>>(src, dst, cursor, sorted_src);

    gemm1_kernel<<<(N_NODES + 127) / 128, 256, 0, stream>>>(X, W1, norm_src, H);
    agg1_kernel<<<(N_NODES + 3) / 4, 256, 0, stream>>>(offsets, sorted_src, H, norm_dst, b1, H1);
    gemm2_kernel<<<(N_NODES + 3) / 4, 256, 0, stream>>>(H1, W2, norm_src, H2);
    agg2_kernel<<<(N_NODES + 3) / 4, 256, 0, stream>>>(offsets, sorted_src, H2, norm_dst, b2, out);
}

// Round 3
// 800.472 us; speedup vs baseline: 5.1906x; 1.0881x over previous
//
#include <hip/hip_runtime.h>

#define N_NODES 50000
#define N_EDGES 1600000
#define IN_FEATS 512
#define N_HIDDEN 128
#define N_CLASSES 40

typedef __attribute__((ext_vector_type(8))) short bf16x8;
typedef __attribute__((ext_vector_type(4))) float f32x4;

__device__ __forceinline__ unsigned short f2bf(float f) {
    unsigned u = __float_as_uint(f);
    u = (u + 0x7FFFu + ((u >> 16) & 1u)) >> 16;   // round-to-nearest-even
    return (unsigned short)u;
}
__device__ __forceinline__ float bf2f(unsigned short h) {
    return __uint_as_float(((unsigned)h) << 16);
}

// ---------------------------------------------------------------------------
__global__ void deg_kernel(const int* __restrict__ src, const int* __restrict__ dst,
                           int* __restrict__ deg_out, int* __restrict__ deg_in) {
    int e = blockIdx.x * blockDim.x + threadIdx.x;
    if (e < N_EDGES) {
        atomicAdd(&deg_out[src[e]], 1);
        atomicAdd(&deg_in[dst[e]], 1);
    }
}

__global__ void norm_kernel(const int* __restrict__ deg_out, const int* __restrict__ deg_in,
                            float* __restrict__ norm_src, float* __restrict__ norm_dst) {
    int n = blockIdx.x * blockDim.x + threadIdx.x;
    if (n < N_NODES) {
        norm_src[n] = rsqrtf(fmaxf((float)deg_out[n], 1.0f));
        norm_dst[n] = rsqrtf(fmaxf((float)deg_in[n], 1.0f));
    }
}

// single-block exclusive scan of deg_in -> offsets[0..N], cursor copy
__global__ __launch_bounds__(1024) void scan_kernel(const int* __restrict__ deg_in,
                                                    int* __restrict__ offsets,
                                                    int* __restrict__ cursor) {
    __shared__ int part[1024];
    const int t = threadIdx.x;
    const int beg = t * 49;
    const int end = min(beg + 49, N_NODES);
    int s = 0;
    for (int i = beg; i < end; i++) s += deg_in[i];
    part[t] = s;
    __syncthreads();
    for (int off = 1; off < 1024; off <<= 1) {
        int v = (t >= off) ? part[t - off] : 0;
        __syncthreads();
        part[t] += v;
        __syncthreads();
    }
    int run = (t == 0) ? 0 : part[t - 1];
    for (int i = beg; i < end; i++) {
        offsets[i] = run;
        cursor[i] = run;
        run += deg_in[i];
    }
    if (t == 1023) offsets[N_NODES] = part[1023];
}

__global__ void fill_kernel(const int* __restrict__ src, const int* __restrict__ dst,
                            int* __restrict__ cursor, int* __restrict__ sorted_src) {
    int e = blockIdx.x * blockDim.x + threadIdx.x;
    if (e < N_EDGES) {
        int pos = atomicAdd(&cursor[dst[e]], 1);
        sorted_src[pos] = src[e];
    }
}

// ---------------------------------------------------------------------------
// pre-convert W1 [512][128] -> transposed bf16 hi/lo [col][k]
__global__ __launch_bounds__(256) void w1cvt_kernel(const float* __restrict__ W1,
                                                    unsigned short* __restrict__ Wth,
                                                    unsigned short* __restrict__ Wtl) {
    int i = blockIdx.x * 256 + threadIdx.x;
    if (i >= IN_FEATS * N_HIDDEN) return;
    int k = i >> 7, c = i & 127;
    float v = W1[i];
    unsigned short h = f2bf(v);
    Wth[c * IN_FEATS + k] = h;
    Wtl[c * IN_FEATS + k] = f2bf(v - bf2f(h));
}

// ---------------------------------------------------------------------------
// GEMM1 via bf16 MFMA, split-precision (xh*wh + xh*wl + xl*wh).
// Block tile 128x128, BK=32, 4 waves in 2x2 grid (each wave 64x64 = 4x4 MFMA tiles).
__global__ __launch_bounds__(256) void gemm1_kernel(
    const float* __restrict__ X, const unsigned short* __restrict__ Wth,
    const unsigned short* __restrict__ Wtl,
    const float* __restrict__ norm_src, float* __restrict__ H) {
    __shared__ __align__(16) unsigned short Xh[128][40];  // pitch 40 (80B) kills b128 conflicts
    __shared__ __align__(16) unsigned short Xl[128][40];
    __shared__ __align__(16) unsigned short Wh[128][40];  // [col][k]
    __shared__ __align__(16) unsigned short Wl[128][40];
    const int tid = threadIdx.x;
    const int lane = tid & 63;
    const int wave = tid >> 6;
    const int wr = (wave & 1) * 64;
    const int wc = (wave >> 1) * 64;
    const int row0 = blockIdx.x * 128;
    const int m = lane & 15;
    const int q = lane >> 4;

    f32x4 acc[4][4];
#pragma unroll
    for (int i = 0; i < 4; i++)
#pragma unroll
        for (int j = 0; j < 4; j++) acc[i][j] = (f32x4){0.f, 0.f, 0.f, 0.f};

    for (int k0 = 0; k0 < IN_FEATS; k0 += 32) {
        // stage X tile (128 rows x 32 k), f32 -> bf16 hi/lo
#pragma unroll
        for (int l = 0; l < 4; l++) {
            int s = tid + l * 256;          // 0..1023
            int r = s >> 3;                 // 0..127
            int kq = (s & 7) * 4;           // 0..28
            float4 v = make_float4(0.f, 0.f, 0.f, 0.f);
            int grow = row0 + r;
            if (grow < N_NODES) v = *(const float4*)&X[(size_t)grow * IN_FEATS + k0 + kq];
            unsigned short h0 = f2bf(v.x), h1 = f2bf(v.y), h2 = f2bf(v.z), h3 = f2bf(v.w);
            unsigned short l0 = f2bf(v.x - bf2f(h0)), l1 = f2bf(v.y - bf2f(h1));
            unsigned short l2 = f2bf(v.z - bf2f(h2)), l3 = f2bf(v.w - bf2f(h3));
            uint2 ph = make_uint2((unsigned)h0 | ((unsigned)h1 << 16),
                                  (unsigned)h2 | ((unsigned)h3 << 16));
            uint2 pl = make_uint2((unsigned)l0 | ((unsigned)l1 << 16),
                                  (unsigned)l2 | ((unsigned)l3 << 16));
            *(uint2*)&Xh[r][kq] = ph;
            *(uint2*)&Xl[r][kq] = pl;
        }
        // stage W tile (128 cols x 32 k), already bf16 transposed in global
#pragma unroll
        for (int l = 0; l < 2; l++) {
            int s = tid + l * 256;          // 0..511
            int c = s >> 2;                 // 0..127
            int kq = (s & 3) * 8;           // 0,8,16,24
            *(uint4*)&Wh[c][kq] = *(const uint4*)&Wth[(size_t)c * IN_FEATS + k0 + kq];
            *(uint4*)&Wl[c][kq] = *(const uint4*)&Wtl[(size_t)c * IN_FEATS + k0 + kq];
        }
        __syncthreads();

        bf16x8 ah[4], al[4], bh[4], bl[4];
#pragma unroll
        for (int i = 0; i < 4; i++) {
            ah[i] = *(const bf16x8*)&Xh[wr + i * 16 + m][q * 8];
            al[i] = *(const bf16x8*)&Xl[wr + i * 16 + m][q * 8];
            bh[i] = *(const bf16x8*)&Wh[wc + i * 16 + m][q * 8];
            bl[i] = *(const bf16x8*)&Wl[wc + i * 16 + m][q * 8];
        }
#pragma unroll
        for (int i = 0; i < 4; i++)
#pragma unroll
            for (int j = 0; j < 4; j++) {
                acc[i][j] = __builtin_amdgcn_mfma_f32_16x16x32_bf16(ah[i], bh[j], acc[i][j], 0, 0, 0);
                acc[i][j] = __builtin_amdgcn_mfma_f32_16x16x32_bf16(ah[i], bl[j], acc[i][j], 0, 0, 0);
                acc[i][j] = __builtin_amdgcn_mfma_f32_16x16x32_bf16(al[i], bh[j], acc[i][j], 0, 0, 0);
            }
        __syncthreads();
    }
    // epilogue: C/D layout col=lane&15, row=(lane>>4)*4+reg
#pragma unroll
    for (int i = 0; i < 4; i++) {
#pragma unroll
        for (int r = 0; r < 4; r++) {
            int grow = row0 + wr + i * 16 + q * 4 + r;
            if (grow < N_NODES) {
                float sc = norm_src[grow];
#pragma unroll
                for (int j = 0; j < 4; j++)
                    H[(size_t)grow * N_HIDDEN + wc + j * 16 + m] = acc[i][j][r] * sc;
            }
        }
    }
}

// ---------------------------------------------------------------------------
// agg1: one wave per dst node; 2 edges x 32 lanes x float4 per step, unroll 4
// (8 edges / 8 b128 loads in flight), xor-32 butterfly, fused norm+bias+relu.
__global__ __launch_bounds__(256) void agg1_kernel(
    const int* __restrict__ offsets, const int* __restrict__ sorted_src,
    const float* __restrict__ H, const float* __restrict__ norm_dst,
    const float* __restrict__ b1, float* __restrict__ H1) {
    int wid = (blockIdx.x * 256 + threadIdx.x) >> 6;
    int lane = threadIdx.x & 63;
    if (wid >= N_NODES) return;
    int start = offsets[wid], end = offsets[wid + 1];
    int half = lane >> 5;
    int f4 = (lane & 31) * 4;
    float4 acc = make_float4(0.f, 0.f, 0.f, 0.f);
    int base = start;
    int nfull = (end - start) & ~7;
    for (; base < start + nfull; base += 8) {
        int e0 = sorted_src[base + half + 0];
        int e1 = sorted_src[base + half + 2];
        int e2 = sorted_src[base + half + 4];
        int e3 = sorted_src[base + half + 6];
        float4 v0 = *(const float4*)&H[(size_t)e0 * N_HIDDEN + f4];
        float4 v1 = *(const float4*)&H[(size_t)e1 * N_HIDDEN + f4];
        float4 v2 = *(const float4*)&H[(size_t)e2 * N_HIDDEN + f4];
        float4 v3 = *(const float4*)&H[(size_t)e3 * N_HIDDEN + f4];
        acc.x += (v0.x + v1.x) + (v2.x + v3.x);
        acc.y += (v0.y + v1.y) + (v2.y + v3.y);
        acc.z += (v0.z + v1.z) + (v2.z + v3.z);
        acc.w += (v0.w + v1.w) + (v2.w + v3.w);
    }
    int rem = end - base;
    int npair = rem & ~1;
    for (int t = 0; t < npair; t += 2) {
        int e = sorted_src[base + t + half];
        float4 v = *(const float4*)&H[(size_t)e * N_HIDDEN + f4];
        acc.x += v.x; acc.y += v.y; acc.z += v.z; acc.w += v.w;
    }
    base += npair;
    if (base < end && half == 0) {
        int e = sorted_src[base];
        float4 v = *(const float4*)&H[(size_t)e * N_HIDDEN + f4];
        acc.x += v.x; acc.y += v.y; acc.z += v.z; acc.w += v.w;
    }
    acc.x += __shfl_xor(acc.x, 32);
    acc.y += __shfl_xor(acc.y, 32);
    acc.z += __shfl_xor(acc.z, 32);
    acc.w += __shfl_xor(acc.w, 32);
    if (half == 0) {
        float nd = norm_dst[wid];
        float4 b = *(const float4*)&b1[f4];
        acc.x = fmaxf(acc.x * nd + b.x, 0.f);
        acc.y = fmaxf(acc.y * nd + b.y, 0.f);
        acc.z = fmaxf(acc.z * nd + b.z, 0.f);
        acc.w = fmaxf(acc.w * nd + b.w, 0.f);
        *(float4*)&H1[(size_t)wid * N_HIDDEN + f4] = acc;
    }
}

// ---------------------------------------------------------------------------
// GEMM2: H2p[n][0:40] = (H1[n,0:128] @ W2) * norm_src[n]; pitch-64 padded out.
__global__ __launch_bounds__(256) void gemm2_kernel(
    const float* __restrict__ H1, const float* __restrict__ W2,
    const float* __restrict__ norm_src, float* __restrict__ H2p) {
    __shared__ float Ws[N_HIDDEN * N_CLASSES + 64];  // pad: lanes 40..63 read junk safely
    int tid = threadIdx.x;
    for (int i = tid; i < N_HIDDEN * N_CLASSES; i += 256) Ws[i] = W2[i];
    __syncthreads();
    int wave = tid >> 6;
    int lane = tid & 63;
    int row = blockIdx.x * 4 + wave;
    if (row >= N_NODES) return;
    const float* h = &H1[(size_t)row * N_HIDDEN];
    float a0 = 0.f, a1 = 0.f, a2 = 0.f, a3 = 0.f;
#pragma unroll
    for (int k = 0; k < N_HIDDEN; k += 4) {
        float4 hv = *(const float4*)&h[k];
        a0 = fmaf(hv.x, Ws[(k + 0) * N_CLASSES + lane], a0);
        a1 = fmaf(hv.y, Ws[(k + 1) * N_CLASSES + lane], a1);
        a2 = fmaf(hv.z, Ws[(k + 2) * N_CLASSES + lane], a2);
        a3 = fmaf(hv.w, Ws[(k + 3) * N_CLASSES + lane], a3);
    }
    if (lane < N_CLASSES)
        H2p[(size_t)row * 64 + lane] = ((a0 + a1) + (a2 + a3)) * norm_src[row];
}

// ---------------------------------------------------------------------------
// agg2: one wave per dst node; 4 edges x 16 lanes x float4 (cols 0..39 live),
// unroll 2 (8 edges in flight), xor-16/32 butterfly.
__global__ __launch_bounds__(256) void agg2_kernel(
    const int* __restrict__ offsets, const int* __restrict__ sorted_src,
    const float* __restrict__ H2p, const float* __restrict__ norm_dst,
    const float* __restrict__ b2, float* __restrict__ OUT) {
    int wid = (blockIdx.x * 256 + threadIdx.x) >> 6;
    int lane = threadIdx.x & 63;
    if (wid >= N_NODES) return;
    int start = offsets[wid], end = offsets[wid + 1];
    int quad = lane >> 4;
    int c4 = (lane & 15) * 4;
    bool active = c4 < N_CLASSES;
    float4 acc = make_float4(0.f, 0.f, 0.f, 0.f);
    int base = start;
    int nfull = (end - start) & ~7;
    for (; base < start + nfull; base += 8) {
        int e0 = sorted_src[base + quad];
        int e1 = sorted_src[base + 4 + quad];
        if (active) {
            float4 v0 = *(const float4*)&H2p[(size_t)e0 * 64 + c4];
            float4 v1 = *(const float4*)&H2p[(size_t)e1 * 64 + c4];
            acc.x += v0.x + v1.x;
            acc.y += v0.y + v1.y;
            acc.z += v0.z + v1.z;
            acc.w += v0.w + v1.w;
        }
    }
    int rem = end - base;
    int n4 = rem & ~3;
    for (int t = 0; t < n4; t += 4) {
        int e = sorted_src[base + t + quad];
        if (active) {
            float4 v = *(const float4*)&H2p[(size_t)e * 64 + c4];
            acc.x += v.x; acc.y += v.y; acc.z += v.z; acc.w += v.w;
        }
    }
    base += n4;
    if (quad < end - base && active) {
        int e = sorted_src[base + quad];
        float4 v = *(const float4*)&H2p[(size_t)e * 64 + c4];
        acc.x += v.x; acc.y += v.y; acc.z += v.z; acc.w += v.w;
    }
    acc.x += __shfl_xor(acc.x, 16); acc.x += __shfl_xor(acc.x, 32);
    acc.y += __shfl_xor(acc.y, 16); acc.y += __shfl_xor(acc.y, 32);
    acc.z += __shfl_xor(acc.z, 16); acc.z += __shfl_xor(acc.z, 32);
    acc.w += __shfl_xor(acc.w, 16); acc.w += __shfl_xor(acc.w, 32);
    if (lane < 10) {
        float nd = norm_dst[wid];
        float4 b = *(const float4*)&b2[lane * 4];
        acc.x = acc.x * nd + b.x;
        acc.y = acc.y * nd + b.y;
        acc.z = acc.z * nd + b.z;
        acc.w = acc.w * nd + b.w;
        *(float4*)&OUT[(size_t)wid * N_CLASSES + lane * 4] = acc;
    }
}

// ---------------------------------------------------------------------------
extern "C" void kernel_launch(void* const* d_in, const int* in_sizes, int n_in,
                              void* d_out, int out_size, void* d_ws, size_t ws_size,
                              hipStream_t stream) {
    const float* X   = (const float*)d_in[0];
    const float* W1  = (const float*)d_in[1];
    const float* b1  = (const float*)d_in[2];
    const float* W2  = (const float*)d_in[3];
    const float* b2  = (const float*)d_in[4];
    const int*   src = (const int*)d_in[5];
    const int*   dst = (const int*)d_in[6];
    float* out = (float*)d_out;

    // workspace layout (same footprint as R2; W1t overlaps H1, H2p overlaps H)
    float* norm_src   = (float*)d_ws;
    float* norm_dst   = norm_src + N_NODES;
    int*   deg_out    = (int*)(norm_dst + N_NODES);
    int*   deg_in     = deg_out + N_NODES;
    int*   offsets    = deg_in + N_NODES;
    int*   cursor     = offsets + N_NODES + 16;
    int*   sorted_src = cursor + N_NODES;
    float* H          = (float*)(sorted_src + N_EDGES);   // 50000*128 f32
    float* H1         = H + (size_t)N_NODES * N_HIDDEN;   // 50000*128 f32
    unsigned short* W1th = (unsigned short*)H1;           // 128KB, dead after gemm1
    unsigned short* W1tl = W1th + IN_FEATS * N_HIDDEN;
    float* H2p        = H;                                // 50000*64, reuse after agg1

    hipMemsetAsync(deg_out, 0, 2 * (size_t)N_NODES * sizeof(int), stream);
    deg_kernel<<<(N_EDGES + 255) / 256, 256, 0, stream>>>(src, dst, deg_out, deg_in);
    norm_kernel<<<(N_NODES + 255) / 256, 256, 0, stream>>>(deg_out, deg_in, norm_src, norm_dst);
    scan_kernel<<<1, 1024, 0, stream>>>(deg_in, offsets, cursor);
    fill_kernel<<<(N_EDGES + 255) / 256, 256, 0, stream>>>(src, dst, cursor, sorted_src);

    w1cvt_kernel<<<(IN_FEATS * N_HIDDEN + 255) / 256, 256, 0, stream>>>(W1, W1th, W1tl);
    gemm1_kernel<<<(N_NODES + 127) / 128, 256, 0, stream>>>(X, W1th, W1tl, norm_src, H);
    agg1_kernel<<<(N_NODES + 3) / 4, 256, 0, stream>>>(offsets, sorted_src, H, norm_dst, b1, H1);
    gemm2_kernel<<<(N_NODES + 3) / 4, 256, 0, stream>>>(H1, W2, norm_src, H2p);
    agg2_kernel<<<(N_NODES + 3) / 4, 256, 0, stream>>>(offsets, sorted_src, H2p, norm_dst, b2, out);
}

// Round 4
// 650.083 us; speedup vs baseline: 6.3914x; 1.2313x over previous
//
#include <hip/hip_runtime.h>

#define N_NODES 50000
#define N_EDGES 1600000
#define IN_FEATS 512
#define N_HIDDEN 128
#define N_CLASSES 40
#define NREP 16

typedef __attribute__((ext_vector_type(8))) short bf16x8;
typedef __attribute__((ext_vector_type(4))) float f32x4;

__device__ __forceinline__ unsigned short f2bf(float f) {
    unsigned u = __float_as_uint(f);
    u = (u + 0x7FFFu + ((u >> 16) & 1u)) >> 16;   // round-to-nearest-even
    return (unsigned short)u;
}
__device__ __forceinline__ float bf2f(unsigned short h) {
    return __uint_as_float(((unsigned)h) << 16);
}

// ---------------------------------------------------------------------------
// counting pass: replicated histograms (16x) to spread atomic contention.
// pos[e] = rank of edge e within (replica, dst) sub-bucket.
__global__ __launch_bounds__(256) void count_kernel(
    const int* __restrict__ src, const int* __restrict__ dst,
    int* __restrict__ cnt_dst, int* __restrict__ cnt_src, int* __restrict__ pos) {
    int e = blockIdx.x * 256 + threadIdx.x;      // grid exact: 6250*256 = N_EDGES
    int r = blockIdx.x & (NREP - 1);
    pos[e] = atomicAdd(&cnt_dst[r * N_NODES + dst[e]], 1);
    atomicAdd(&cnt_src[r * N_NODES + src[e]], 1);
}

// per-node: replica prefix (repbase), total in-degree (degin), both norms
__global__ __launch_bounds__(256) void repnorm_kernel(
    const int* __restrict__ cnt_dst, const int* __restrict__ cnt_src,
    int* __restrict__ repbase, int* __restrict__ degin,
    float* __restrict__ norm_src, float* __restrict__ norm_dst) {
    int n = blockIdx.x * 256 + threadIdx.x;
    if (n >= N_NODES) return;
    int tot = 0;
#pragma unroll
    for (int r = 0; r < NREP; r++) {
        repbase[r * N_NODES + n] = tot;
        tot += cnt_dst[r * N_NODES + n];
    }
    degin[n] = tot;
    int so = 0;
#pragma unroll
    for (int r = 0; r < NREP; r++) so += cnt_src[r * N_NODES + n];
    norm_dst[n] = rsqrtf(fmaxf((float)tot, 1.0f));
    norm_src[n] = rsqrtf(fmaxf((float)so, 1.0f));
}

// single-block exclusive scan of degin -> offsets[0..N]
__global__ __launch_bounds__(1024) void scan_kernel(const int* __restrict__ degin,
                                                    int* __restrict__ offsets) {
    __shared__ int part[1024];
    const int t = threadIdx.x;
    const int beg = t * 49;
    const int end = min(beg + 49, N_NODES);
    int s = 0;
    for (int i = beg; i < end; i++) s += degin[i];
    part[t] = s;
    __syncthreads();
    for (int off = 1; off < 1024; off <<= 1) {
        int v = (t >= off) ? part[t - off] : 0;
        __syncthreads();
        part[t] += v;
        __syncthreads();
    }
    int run = (t == 0) ? 0 : part[t - 1];
    for (int i = beg; i < end; i++) {
        offsets[i] = run;
        run += degin[i];
    }
    if (t == 1023) offsets[N_NODES] = part[1023];
}

// atomic-free scatter: position fully determined by offsets+repbase+pos
__global__ __launch_bounds__(256) void scatter_kernel(
    const int* __restrict__ src, const int* __restrict__ dst,
    const int* __restrict__ offsets, const int* __restrict__ repbase,
    const int* __restrict__ pos, int* __restrict__ sorted_src) {
    int e = blockIdx.x * 256 + threadIdx.x;      // grid identical to count_kernel
    int r = blockIdx.x & (NREP - 1);
    int d = dst[e];
    sorted_src[offsets[d] + repbase[r * N_NODES + d] + pos[e]] = src[e];
}

// ---------------------------------------------------------------------------
// pre-convert W1 [512][128] -> transposed bf16 hi/lo [col][k]
__global__ __launch_bounds__(256) void w1cvt_kernel(const float* __restrict__ W1,
                                                    unsigned short* __restrict__ Wth,
                                                    unsigned short* __restrict__ Wtl) {
    int i = blockIdx.x * 256 + threadIdx.x;
    if (i >= IN_FEATS * N_HIDDEN) return;
    int k = i >> 7, c = i & 127;
    float v = W1[i];
    unsigned short h = f2bf(v);
    Wth[c * IN_FEATS + k] = h;
    Wtl[c * IN_FEATS + k] = f2bf(v - bf2f(h));
}

// ---------------------------------------------------------------------------
// GEMM1 via bf16 MFMA, split-precision (xh*wh + xh*wl + xl*wh).
// Block tile 128x128, BK=32, 4 waves in 2x2 grid. Output H in bf16.
__global__ __launch_bounds__(256) void gemm1_kernel(
    const float* __restrict__ X, const unsigned short* __restrict__ Wth,
    const unsigned short* __restrict__ Wtl,
    const float* __restrict__ norm_src, unsigned short* __restrict__ Hb) {
    __shared__ __align__(16) unsigned short Xh[128][40];
    __shared__ __align__(16) unsigned short Xl[128][40];
    __shared__ __align__(16) unsigned short Wh[128][40];
    __shared__ __align__(16) unsigned short Wl[128][40];
    const int tid = threadIdx.x;
    const int lane = tid & 63;
    const int wave = tid >> 6;
    const int wr = (wave & 1) * 64;
    const int wc = (wave >> 1) * 64;
    const int row0 = blockIdx.x * 128;
    const int m = lane & 15;
    const int q = lane >> 4;

    f32x4 acc[4][4];
#pragma unroll
    for (int i = 0; i < 4; i++)
#pragma unroll
        for (int j = 0; j < 4; j++) acc[i][j] = (f32x4){0.f, 0.f, 0.f, 0.f};

    for (int k0 = 0; k0 < IN_FEATS; k0 += 32) {
#pragma unroll
        for (int l = 0; l < 4; l++) {
            int s = tid + l * 256;
            int r = s >> 3;
            int kq = (s & 7) * 4;
            float4 v = make_float4(0.f, 0.f, 0.f, 0.f);
            int grow = row0 + r;
            if (grow < N_NODES) v = *(const float4*)&X[(size_t)grow * IN_FEATS + k0 + kq];
            unsigned short h0 = f2bf(v.x), h1 = f2bf(v.y), h2 = f2bf(v.z), h3 = f2bf(v.w);
            unsigned short l0 = f2bf(v.x - bf2f(h0)), l1 = f2bf(v.y - bf2f(h1));
            unsigned short l2 = f2bf(v.z - bf2f(h2)), l3 = f2bf(v.w - bf2f(h3));
            uint2 ph = make_uint2((unsigned)h0 | ((unsigned)h1 << 16),
                                  (unsigned)h2 | ((unsigned)h3 << 16));
            uint2 pl = make_uint2((unsigned)l0 | ((unsigned)l1 << 16),
                                  (unsigned)l2 | ((unsigned)l3 << 16));
            *(uint2*)&Xh[r][kq] = ph;
            *(uint2*)&Xl[r][kq] = pl;
        }
#pragma unroll
        for (int l = 0; l < 2; l++) {
            int s = tid + l * 256;
            int c = s >> 2;
            int kq = (s & 3) * 8;
            *(uint4*)&Wh[c][kq] = *(const uint4*)&Wth[(size_t)c * IN_FEATS + k0 + kq];
            *(uint4*)&Wl[c][kq] = *(const uint4*)&Wtl[(size_t)c * IN_FEATS + k0 + kq];
        }
        __syncthreads();

        bf16x8 ah[4], al[4], bh[4], bl[4];
#pragma unroll
        for (int i = 0; i < 4; i++) {
            ah[i] = *(const bf16x8*)&Xh[wr + i * 16 + m][q * 8];
            al[i] = *(const bf16x8*)&Xl[wr + i * 16 + m][q * 8];
            bh[i] = *(const bf16x8*)&Wh[wc + i * 16 + m][q * 8];
            bl[i] = *(const bf16x8*)&Wl[wc + i * 16 + m][q * 8];
        }
#pragma unroll
        for (int i = 0; i < 4; i++)
#pragma unroll
            for (int j = 0; j < 4; j++) {
                acc[i][j] = __builtin_amdgcn_mfma_f32_16x16x32_bf16(ah[i], bh[j], acc[i][j], 0, 0, 0);
                acc[i][j] = __builtin_amdgcn_mfma_f32_16x16x32_bf16(ah[i], bl[j], acc[i][j], 0, 0, 0);
                acc[i][j] = __builtin_amdgcn_mfma_f32_16x16x32_bf16(al[i], bh[j], acc[i][j], 0, 0, 0);
            }
        __syncthreads();
    }
    // epilogue: C/D layout col=lane&15, row=(lane>>4)*4+reg; store bf16
#pragma unroll
    for (int i = 0; i < 4; i++) {
#pragma unroll
        for (int r = 0; r < 4; r++) {
            int grow = row0 + wr + i * 16 + q * 4 + r;
            if (grow < N_NODES) {
                float sc = norm_src[grow];
#pragma unroll
                for (int j = 0; j < 4; j++)
                    Hb[(size_t)grow * N_HIDDEN + wc + j * 16 + m] = f2bf(acc[i][j][r] * sc);
            }
        }
    }
}

// ---------------------------------------------------------------------------
// agg1: one wave per dst node; 4 edges x 16 lanes x bf16x8 (uint4) per step,
// unroll 2 (8 b128 loads in flight), f32 accum, xor-16/32 butterfly,
// fused norm+bias+relu. H1 out in f32.
#define ADD8(W)                                               \
    acc0 += __uint_as_float((W).x << 16);                     \
    acc1 += __uint_as_float((W).x & 0xffff0000u);             \
    acc2 += __uint_as_float((W).y << 16);                     \
    acc3 += __uint_as_float((W).y & 0xffff0000u);             \
    acc4 += __uint_as_float((W).z << 16);                     \
    acc5 += __uint_as_float((W).z & 0xffff0000u);             \
    acc6 += __uint_as_float((W).w << 16);                     \
    acc7 += __uint_as_float((W).w & 0xffff0000u);

__global__ __launch_bounds__(256) void agg1_kernel(
    const int* __restrict__ offsets, const int* __restrict__ sorted_src,
    const unsigned short* __restrict__ Hb, const float* __restrict__ norm_dst,
    const float* __restrict__ b1, float* __restrict__ H1) {
    int wid = (blockIdx.x * 256 + threadIdx.x) >> 6;
    int lane = threadIdx.x & 63;
    if (wid >= N_NODES) return;
    int start = offsets[wid], end = offsets[wid + 1];
    int quad = lane >> 4;
    int c8 = (lane & 15) * 8;
    float acc0 = 0.f, acc1 = 0.f, acc2 = 0.f, acc3 = 0.f;
    float acc4 = 0.f, acc5 = 0.f, acc6 = 0.f, acc7 = 0.f;
    int base = start;
    for (; base + 8 <= end; base += 8) {
        int e0 = sorted_src[base + quad];
        int e1 = sorted_src[base + 4 + quad];
        uint4 w0 = *(const uint4*)&Hb[(size_t)e0 * N_HIDDEN + c8];
        uint4 w1 = *(const uint4*)&Hb[(size_t)e1 * N_HIDDEN + c8];
        ADD8(w0);
        ADD8(w1);
    }
    int rem = end - base;
    if (quad < rem) {
        int e = sorted_src[base + quad];
        uint4 w = *(const uint4*)&Hb[(size_t)e * N_HIDDEN + c8];
        ADD8(w);
    }
    if (quad + 4 < rem) {
        int e = sorted_src[base + 4 + quad];
        uint4 w = *(const uint4*)&Hb[(size_t)e * N_HIDDEN + c8];
        ADD8(w);
    }
    acc0 += __shfl_xor(acc0, 16); acc0 += __shfl_xor(acc0, 32);
    acc1 += __shfl_xor(acc1, 16); acc1 += __shfl_xor(acc1, 32);
    acc2 += __shfl_xor(acc2, 16); acc2 += __shfl_xor(acc2, 32);
    acc3 += __shfl_xor(acc3, 16); acc3 += __shfl_xor(acc3, 32);
    acc4 += __shfl_xor(acc4, 16); acc4 += __shfl_xor(acc4, 32);
    acc5 += __shfl_xor(acc5, 16); acc5 += __shfl_xor(acc5, 32);
    acc6 += __shfl_xor(acc6, 16); acc6 += __shfl_xor(acc6, 32);
    acc7 += __shfl_xor(acc7, 16); acc7 += __shfl_xor(acc7, 32);
    if (quad == 0) {
        float nd = norm_dst[wid];
        float4 ba = *(const float4*)&b1[c8];
        float4 bb = *(const float4*)&b1[c8 + 4];
        float4 o0 = make_float4(fmaxf(acc0 * nd + ba.x, 0.f), fmaxf(acc1 * nd + ba.y, 0.f),
                                fmaxf(acc2 * nd + ba.z, 0.f), fmaxf(acc3 * nd + ba.w, 0.f));
        float4 o1 = make_float4(fmaxf(acc4 * nd + bb.x, 0.f), fmaxf(acc5 * nd + bb.y, 0.f),
                                fmaxf(acc6 * nd + bb.z, 0.f), fmaxf(acc7 * nd + bb.w, 0.f));
        *(float4*)&H1[(size_t)wid * N_HIDDEN + c8] = o0;
        *(float4*)&H1[(size_t)wid * N_HIDDEN + c8 + 4] = o1;
    }
}

// ---------------------------------------------------------------------------
// GEMM2: H2p[n][0:40] = (H1[n,0:128] @ W2) * norm_src[n]; pitch-64 padded out.
__global__ __launch_bounds__(256) void gemm2_kernel(
    const float* __restrict__ H1, const float* __restrict__ W2,
    const float* __restrict__ norm_src, float* __restrict__ H2p) {
    __shared__ float Ws[N_HIDDEN * N_CLASSES + 64];
    int tid = threadIdx.x;
    for (int i = tid; i < N_HIDDEN * N_CLASSES; i += 256) Ws[i] = W2[i];
    __syncthreads();
    int wave = tid >> 6;
    int lane = tid & 63;
    int row = blockIdx.x * 4 + wave;
    if (row >= N_NODES) return;
    const float* h = &H1[(size_t)row * N_HIDDEN];
    float a0 = 0.f, a1 = 0.f, a2 = 0.f, a3 = 0.f;
#pragma unroll
    for (int k = 0; k < N_HIDDEN; k += 4) {
        float4 hv = *(const float4*)&h[k];
        a0 = fmaf(hv.x, Ws[(k + 0) * N_CLASSES + lane], a0);
        a1 = fmaf(hv.y, Ws[(k + 1) * N_CLASSES + lane], a1);
        a2 = fmaf(hv.z, Ws[(k + 2) * N_CLASSES + lane], a2);
        a3 = fmaf(hv.w, Ws[(k + 3) * N_CLASSES + lane], a3);
    }
    if (lane < N_CLASSES)
        H2p[(size_t)row * 64 + lane] = ((a0 + a1) + (a2 + a3)) * norm_src[row];
}

// ---------------------------------------------------------------------------
// agg2: one wave per dst node; 4 edges x 16 lanes x float4, unroll 2.
__global__ __launch_bounds__(256) void agg2_kernel(
    const int* __restrict__ offsets, const int* __restrict__ sorted_src,
    const float* __restrict__ H2p, const float* __restrict__ norm_dst,
    const float* __restrict__ b2, float* __restrict__ OUT) {
    int wid = (blockIdx.x * 256 + threadIdx.x) >> 6;
    int lane = threadIdx.x & 63;
    if (wid >= N_NODES) return;
    int start = offsets[wid], end = offsets[wid + 1];
    int quad = lane >> 4;
    int c4 = (lane & 15) * 4;
    bool active = c4 < N_CLASSES;
    float4 acc = make_float4(0.f, 0.f, 0.f, 0.f);
    int base = start;
    int nfull = (end - start) & ~7;
    for (; base < start + nfull; base += 8) {
        int e0 = sorted_src[base + quad];
        int e1 = sorted_src[base + 4 + quad];
        if (active) {
            float4 v0 = *(const float4*)&H2p[(size_t)e0 * 64 + c4];
            float4 v1 = *(const float4*)&H2p[(size_t)e1 * 64 + c4];
            acc.x += v0.x + v1.x;
            acc.y += v0.y + v1.y;
            acc.z += v0.z + v1.z;
            acc.w += v0.w + v1.w;
        }
    }
    int rem = end - base;
    int n4 = rem & ~3;
    for (int t = 0; t < n4; t += 4) {
        int e = sorted_src[base + t + quad];
        if (active) {
            float4 v = *(const float4*)&H2p[(size_t)e * 64 + c4];
            acc.x += v.x; acc.y += v.y; acc.z += v.z; acc.w += v.w;
        }
    }
    base += n4;
    if (quad < end - base && active) {
        int e = sorted_src[base + quad];
        float4 v = *(const float4*)&H2p[(size_t)e * 64 + c4];
        acc.x += v.x; acc.y += v.y; acc.z += v.z; acc.w += v.w;
    }
    acc.x += __shfl_xor(acc.x, 16); acc.x += __shfl_xor(acc.x, 32);
    acc.y += __shfl_xor(acc.y, 16); acc.y += __shfl_xor(acc.y, 32);
    acc.z += __shfl_xor(acc.z, 16); acc.z += __shfl_xor(acc.z, 32);
    acc.w += __shfl_xor(acc.w, 16); acc.w += __shfl_xor(acc.w, 32);
    if (lane < 10) {
        float nd = norm_dst[wid];
        float4 b = *(const float4*)&b2[lane * 4];
        acc.x = acc.x * nd + b.x;
        acc.y = acc.y * nd + b.y;
        acc.z = acc.z * nd + b.z;
        acc.w = acc.w * nd + b.w;
        *(float4*)&OUT[(size_t)wid * N_CLASSES + lane * 4] = acc;
    }
}

// ---------------------------------------------------------------------------
extern "C" void kernel_launch(void* const* d_in, const int* in_sizes, int n_in,
                              void* d_out, int out_size, void* d_ws, size_t ws_size,
                              hipStream_t stream) {
    const float* X   = (const float*)d_in[0];
    const float* W1  = (const float*)d_in[1];
    const float* b1  = (const float*)d_in[2];
    const float* W2  = (const float*)d_in[3];
    const float* b2  = (const float*)d_in[4];
    const int*   src = (const int*)d_in[5];
    const int*   dst = (const int*)d_in[6];
    float* out = (float*)d_out;

    // workspace layout (4B units). Region A (3.2M dwords) is time-shared:
    //   phase 1: cnt_dst (800K) + cnt_src (800K)   [dead after repnorm]
    //   phase 2: Hb bf16 50000x128 (1.6M dwords)   [dead after agg1]
    //   phase 3: H2p f32 50000x64 (3.2M dwords)
    float* norm_src   = (float*)d_ws;
    float* norm_dst   = norm_src + N_NODES;
    int*   degin      = (int*)(norm_dst + N_NODES);
    int*   offsets    = degin + N_NODES;                  // N_NODES+1 (+15 pad)
    int*   repbase    = offsets + N_NODES + 16;           // NREP*N_NODES
    int*   pos        = repbase + NREP * N_NODES;         // N_EDGES
    int*   sorted_src = pos + N_EDGES;                    // N_EDGES
    int*   regionA    = sorted_src + N_EDGES;             // 3.2M dwords
    int*   cnt_dst    = regionA;
    int*   cnt_src    = regionA + NREP * N_NODES;
    unsigned short* Hb = (unsigned short*)regionA;
    float* H2p        = (float*)regionA;
    float* H1         = (float*)(regionA + 3200000);      // 1.6M f32
    unsigned short* W1th = (unsigned short*)(H1 + (size_t)N_NODES * N_HIDDEN);
    unsigned short* W1tl = W1th + IN_FEATS * N_HIDDEN;

    hipMemsetAsync(cnt_dst, 0, 2 * (size_t)NREP * N_NODES * sizeof(int), stream);
    count_kernel<<<N_EDGES / 256, 256, 0, stream>>>(src, dst, cnt_dst, cnt_src, pos);
    repnorm_kernel<<<(N_NODES + 255) / 256, 256, 0, stream>>>(cnt_dst, cnt_src, repbase, degin,
                                                              norm_src, norm_dst);
    scan_kernel<<<1, 1024, 0, stream>>>(degin, offsets);
    scatter_kernel<<<N_EDGES / 256, 256, 0, stream>>>(src, dst, offsets, repbase, pos, sorted_src);

    w1cvt_kernel<<<(IN_FEATS * N_HIDDEN + 255) / 256, 256, 0, stream>>>(W1, W1th, W1tl);
    gemm1_kernel<<<(N_NODES + 127) / 128, 256, 0, stream>>>(X, W1th, W1tl, norm_src, Hb);
    agg1_kernel<<<(N_NODES + 3) / 4, 256, 0, stream>>>(offsets, sorted_src, Hb, norm_dst, b1, H1);
    gemm2_kernel<<<(N_NODES + 3) / 4, 256, 0, stream>>>(H1, W2, norm_src, H2p);
    agg2_kernel<<<(N_NODES + 3) / 4, 256, 0, stream>>>(offsets, sorted_src, H2p, norm_dst, b2, out);
}